// Round 2
// baseline (693.334 us; speedup 1.0000x reference)
//
#include <hip/hip_runtime.h>
#include <math.h>

#define BB 32          // pairs
#define SS 2048        // seq len
#define HH 1024        // hidden
#define NROWS (2 * BB * SS)   // 131072 row-dot-products

// ---------------------------------------------------------------------------
// Kernel 1: rewards[row] = dot(hidden[row, :], w)
// One wave per row-group; each wave processes 4 rows per iteration with
// 16 independent float4 loads in flight and 4 interleaved butterfly
// reductions. Each wave owns a contiguous 64 KiB chunk (16 rows) — the
// same sequential-stream pattern as the 6.3 TB/s copy microbench.
// ---------------------------------------------------------------------------
__global__ __launch_bounds__(256) void rewards_kernel(
    const float* __restrict__ hs, const float* __restrict__ w,
    float* __restrict__ rewards)
{
    const int lane = threadIdx.x & 63;
    const int wave_in_block = threadIdx.x >> 6;
    const int wave_id = blockIdx.x * 4 + wave_in_block;
    const int nwaves = gridDim.x * 4;                 // 8192
    const int rows_per_wave = NROWS / nwaves;         // 16

    // lane covers h = lane*4 + k*256, k = 0..3  (covers 0..1023 exactly)
    float4 wv[4];
#pragma unroll
    for (int k = 0; k < 4; ++k)
        wv[k] = *reinterpret_cast<const float4*>(w + lane * 4 + k * 256);

    const size_t base = (size_t)wave_id * rows_per_wave;

    for (int it = 0; it < rows_per_wave; it += 4) {
        const float* r0 = hs + (base + it + 0) * HH + lane * 4;
        const float* r1 = hs + (base + it + 1) * HH + lane * 4;
        const float* r2 = hs + (base + it + 2) * HH + lane * 4;
        const float* r3 = hs + (base + it + 3) * HH + lane * 4;

        float a0 = 0.f, a1 = 0.f, a2 = 0.f, a3 = 0.f;
#pragma unroll
        for (int k = 0; k < 4; ++k) {
            float4 h0 = *reinterpret_cast<const float4*>(r0 + k * 256);
            float4 h1 = *reinterpret_cast<const float4*>(r1 + k * 256);
            float4 h2 = *reinterpret_cast<const float4*>(r2 + k * 256);
            float4 h3 = *reinterpret_cast<const float4*>(r3 + k * 256);
            a0 += h0.x * wv[k].x + h0.y * wv[k].y + h0.z * wv[k].z + h0.w * wv[k].w;
            a1 += h1.x * wv[k].x + h1.y * wv[k].y + h1.z * wv[k].z + h1.w * wv[k].w;
            a2 += h2.x * wv[k].x + h2.y * wv[k].y + h2.z * wv[k].z + h2.w * wv[k].w;
            a3 += h3.x * wv[k].x + h3.y * wv[k].y + h3.z * wv[k].z + h3.w * wv[k].w;
        }
        // 4 interleaved butterflies — independent chains hide shuffle latency
#pragma unroll
        for (int off = 32; off > 0; off >>= 1) {
            a0 += __shfl_xor(a0, off, 64);
            a1 += __shfl_xor(a1, off, 64);
            a2 += __shfl_xor(a2, off, 64);
            a3 += __shfl_xor(a3, off, 64);
        }
        if (lane == 0) {
            float4 outv = make_float4(a0, a1, a2, a3);
            *reinterpret_cast<float4*>(rewards + base + it) = outv;
        }
    }
}

// ---------------------------------------------------------------------------
// Block-wide helpers (256 threads)
// ---------------------------------------------------------------------------
__device__ __forceinline__ int block_min_i(int v, int* sm, int tid) {
    sm[tid] = v;
    __syncthreads();
    for (int s = 128; s > 0; s >>= 1) {
        if (tid < s) sm[tid] = min(sm[tid], sm[tid + s]);
        __syncthreads();
    }
    int r = sm[0];
    __syncthreads();
    return r;
}

__device__ __forceinline__ float block_sum_f(float v, float* sm, int tid) {
    sm[tid] = v;
    __syncthreads();
    for (int s = 128; s > 0; s >>= 1) {
        if (tid < s) sm[tid] += sm[tid + s];
        __syncthreads();
    }
    float r = sm[0];
    __syncthreads();
    return r;
}

// ---------------------------------------------------------------------------
// Kernel 2: one block per pair b.
// ---------------------------------------------------------------------------
__global__ __launch_bounds__(256) void pair_kernel(
    const int* __restrict__ ids, const float* __restrict__ rewards,
    float* __restrict__ out, float* __restrict__ pp, float* __restrict__ accf)
{
    const int b = blockIdx.x;
    const int tid = threadIdx.x;
    const int* ic = ids + b * SS;
    const int* ir = ids + (BB + b) * SS;
    const float* rc = rewards + b * SS;
    const float* rr = rewards + (BB + b) * SS;

    __shared__ int smi[256];
    __shared__ float smf[256];

    int cmin = SS, rmin = SS, dmin = SS;
    for (int i = tid; i < SS; i += 256) {
        int a = ic[i];
        int c = ir[i];
        if (a == 0 && i < cmin) cmin = i;
        if (c == 0 && i < rmin) rmin = i;
        if (a != c && i < dmin) dmin = i;
    }
    const int c_ind     = block_min_i(cmin, smi, tid);
    const int r_ind_pad = block_min_i(rmin, smi, tid);
    const int dv        = block_min_i(dmin, smi, tid);

    const bool has_div = (dv < SS);
    const int div_ind = has_div ? dv : (SS - 1);
    const int r_ind   = has_div ? r_ind_pad : c_ind;
    const int end_ind = has_div ? max(c_ind, r_ind_pad) : SS;
    const float cnt = fmaxf((float)(end_ind - div_ind), 1.0f);

    float s1 = 0.f, s2 = 0.f, s3 = 0.f;
    for (int i = div_ind + tid; i < end_ind; i += 256) {
        const float c = rc[i];
        const float r = rr[i];
        const float x = c - r;
        // numerically-stable log_sigmoid
        s1 += fminf(x, 0.f) - log1pf(expf(-fabsf(x)));
        s2 += 1.f / (1.f + expf(-c));
        s3 += 1.f / (1.f + expf(-r));
    }
    s1 = block_sum_f(s1, smf, tid);
    s2 = block_sum_f(s2, smf, tid);
    s3 = block_sum_f(s3, smf, tid);

    if (tid == 0) {
        pp[b] = s1 / cnt;
        const float diff_score = (s2 - s3) / cnt;
        accf[b] = (diff_score > 0.5f) ? 1.f : 0.f;
        out[2 + b]      = rc[c_ind - 1];   // chosen_mean_score
        out[2 + BB + b] = rr[r_ind - 1];   // rejected_mean_score
    }
}

// ---------------------------------------------------------------------------
// Kernel 3: final reduction over 32 pairs -> loss, acc
// ---------------------------------------------------------------------------
__global__ __launch_bounds__(64) void final_kernel(
    const float* __restrict__ pp, const float* __restrict__ accf,
    float* __restrict__ out)
{
    const int lane = threadIdx.x;
    float v = (lane < BB) ? pp[lane] : 0.f;
    float a = (lane < BB) ? accf[lane] : 0.f;
#pragma unroll
    for (int off = 32; off > 0; off >>= 1) {
        v += __shfl_xor(v, off, 64);
        a += __shfl_xor(a, off, 64);
    }
    if (lane == 0) {
        out[0] = -v;   // loss
        out[1] = a;    // acc (read back as float32)
    }
}

extern "C" void kernel_launch(void* const* d_in, const int* in_sizes, int n_in,
                              void* d_out, int out_size, void* d_ws, size_t ws_size,
                              hipStream_t stream) {
    const int*   ids = (const int*)d_in[0];     // (2B, S) int32
    const float* hs  = (const float*)d_in[1];   // (2B, S, H) fp32
    const float* w   = (const float*)d_in[2];   // (H,) fp32
    float* out = (float*)d_out;                 // 66 floats

    float* rewards = (float*)d_ws;              // 2B*S floats = 512 KiB
    float* pp      = rewards + NROWS;           // 32 floats
    float* accf    = pp + BB;                   // 32 floats

    rewards_kernel<<<2048, 256, 0, stream>>>(hs, w, rewards);
    pair_kernel<<<BB, 256, 0, stream>>>(ids, rewards, out, pp, accf);
    final_kernel<<<1, 64, 0, stream>>>(pp, accf, out);
}